// Round 2
// baseline (1384.709 us; speedup 1.0000x reference)
//
#include <hip/hip_runtime.h>
#include <stdint.h>

// out[b,:] = tanh(relu(W1[x[b]] + b1) @ W2 + b2)
// B=524288, K=256, N=128. Latency-bound gather -> maximize waves/CU + MLP.

using frag_ab = __attribute__((ext_vector_type(8))) short;  // 8 bf16 (4 VGPRs)
using f32x4   = __attribute__((ext_vector_type(4))) float;  // MFMA acc / stores

__device__ __forceinline__ unsigned int pack_bf16_rne(float a, float b) {
    unsigned int ua = __float_as_uint(a);
    unsigned int ub = __float_as_uint(b);
    ua = (ua + 0x7fffu + ((ua >> 16) & 1u)) >> 16;
    ub = (ub + 0x7fffu + ((ub >> 16) & 1u)) & 0xffff0000u;
    return ua | ub;
}

// 512 blocks x 512 threads: 2 blocks/CU (LDS 65.5 KiB/block), 16 waves/CU (50% occ).
// VGPR capped at 128 via launch_bounds (4 waves/SIMD).
__global__ __launch_bounds__(512, 4)
void hubs_kernel(const int* __restrict__ x,
                 const float* __restrict__ W1,
                 const float* __restrict__ b1,
                 const float* __restrict__ W2,
                 const float* __restrict__ b2,
                 float* __restrict__ out,
                 int strips_per_wave)
{
    // W2 pre-packed as bf16 MFMA fragments: frag f = kt*8+mt, [f][lane][8 bf16].
    // Used as the A operand: lane holds A[m=lane&15][k=quad*8+j] = W2[k][m-col].
    __shared__ unsigned short ldsB[64 * 64 * 8];   // 64 KiB
    __shared__ float ldsB1[256];                   // b1, broadcast reads

    const int tid  = threadIdx.x;
    const int lane = tid & 63;
    const int wave = tid >> 6;
    const int l15  = lane & 15;
    const int quad = lane >> 4;

    for (int idx = tid; idx < 16384; idx += 512) {
        const int j2 = idx & 3;
        const int lf = (idx >> 2) & 63;
        const int fr = idx >> 8;           // kt*8 + mt
        const int kt = fr >> 3;
        const int mt = fr & 7;
        const int m  = mt * 16 + (lf & 15);
        const int k  = kt * 32 + (lf >> 4) * 8 + j2 * 2;
        ((unsigned int*)ldsB)[idx] =
            pack_bf16_rne(W2[k * 128 + m], W2[(k + 1) * 128 + m]);
    }
    if (tid < 256) ldsB1[tid] = b1[tid];

    // b2 per-lane: out-col = mt*16 + quad*4 + r  (matches D layout after swap)
    f32x4 b2v[8];
    #pragma unroll
    for (int mt = 0; mt < 8; ++mt) b2v[mt] = *(const f32x4*)&b2[mt*16 + quad*4];

    __syncthreads();   // only barrier

    const int gw   = blockIdx.x * 8 + wave;          // 0..4095
    const long base = (long)gw * strips_per_wave * 16;

    int row_cur = x[base + l15];
    for (int s = 0; s < strips_per_wave; ++s) {
        const long rowbase = base + (long)s * 16;

        // gather: B-frag(h) lane holds h[row=l15][k=quad*8+j]
        const float* rowptr = W1 + (size_t)row_cur * 256 + quad * 8;
        float4 av[16];
        #pragma unroll
        for (int kt = 0; kt < 8; ++kt) {
            av[2*kt]   = *(const float4*)(rowptr + kt*32);
            av[2*kt+1] = *(const float4*)(rowptr + kt*32 + 4);
        }
        // prefetch next strip's gather index (breaks x->gather serial chain)
        const int row_next = (s + 1 < strips_per_wave) ? x[rowbase + 16 + l15] : 0;

        f32x4 acc[8];
        #pragma unroll
        for (int mt = 0; mt < 8; ++mt) acc[mt] = (f32x4){0.f, 0.f, 0.f, 0.f};

        #pragma unroll
        for (int kt = 0; kt < 8; ++kt) {
            const float4 c0 = *(const float4*)&ldsB1[kt*32 + quad*8];
            const float4 c1 = *(const float4*)&ldsB1[kt*32 + quad*8 + 4];
            const float4 a0 = av[2*kt], a1 = av[2*kt+1];
            const float h0 = fmaxf(a0.x + c0.x, 0.f);
            const float h1 = fmaxf(a0.y + c0.y, 0.f);
            const float h2 = fmaxf(a0.z + c0.z, 0.f);
            const float h3 = fmaxf(a0.w + c0.w, 0.f);
            const float h4 = fmaxf(a1.x + c1.x, 0.f);
            const float h5 = fmaxf(a1.y + c1.y, 0.f);
            const float h6 = fmaxf(a1.z + c1.z, 0.f);
            const float h7 = fmaxf(a1.w + c1.w, 0.f);
            union { frag_ab f; unsigned int u[4]; } H;
            H.u[0] = pack_bf16_rne(h0, h1);
            H.u[1] = pack_bf16_rne(h2, h3);
            H.u[2] = pack_bf16_rne(h4, h5);
            H.u[3] = pack_bf16_rne(h6, h7);
            #pragma unroll
            for (int mt = 0; mt < 8; ++mt) {
                const frag_ab wf = *(const frag_ab*)&ldsB[((kt*8 + mt)*64 + lane)*8];
                // D = A*B with A=W2-frag, B=h-frag -> lane owns D[m=quad*4+r][n=l15]
                acc[mt] = __builtin_amdgcn_mfma_f32_16x16x32_bf16(wf, H.f, acc[mt], 0, 0, 0);
            }
        }
        row_cur = row_next;

        // epilogue: lane writes 4 consecutive cols (mt*16+quad*4..+3) of row l15
        float* orow = out + (size_t)(rowbase + l15) * 128;
        #pragma unroll
        for (int mt = 0; mt < 8; ++mt) {
            f32x4 z = acc[mt] + b2v[mt];
            f32x4 t;
            #pragma unroll
            for (int r = 0; r < 4; ++r) {
                const float zz = z[r], z2 = zz * zz;
                t[r] = zz * (1.0f + z2 * (-0.33333333f + z2 * 0.13333333f));
            }
            __builtin_nontemporal_store(t, (f32x4*)(orow + mt*16 + quad*4));
        }
    }
}

extern "C" void kernel_launch(void* const* d_in, const int* in_sizes, int n_in,
                              void* d_out, int out_size, void* d_ws, size_t ws_size,
                              hipStream_t stream) {
    const int*   x  = (const int*)d_in[0];
    const float* W1 = (const float*)d_in[1];
    const float* b1 = (const float*)d_in[2];
    const float* W2 = (const float*)d_in[3];
    const float* b2 = (const float*)d_in[4];
    float* out = (float*)d_out;

    const int batch        = in_sizes[0];            // 524288
    const int total_strips = batch / 16;             // 32768
    const int grid         = 512;                    // 2 blocks/CU
    const int spw          = total_strips / (grid * 8);  // 8 strips per wave

    hipLaunchKernelGGL(hubs_kernel, dim3(grid), dim3(512), 0, stream,
                       x, W1, b1, W2, b2, out, spw);
}